// Round 20
// baseline (5042.789 us; speedup 1.0000x reference)
//
#include <hip/hip_runtime.h>
#include <math.h>

// STCCapsNet forward. B=32, C=1, H=W=64, HP=WP=28, IN_CAPS=25088, OUT 32x2x16.
// Round 20 (numerics-neutral tail opts):
//  - conv3x3 MFMA: dual-plane A staging (one global read/chunk -> hi+lo LDS), 2 barriers/chunk
//  - route_fin folded into route_fsj prologue (sjp ping-pong buffers)
//  - conv1d x3 fused into one LDS-chained kernel (temporal_k)
// conv9x9 = r15 fp16 2-pass; fuse = r17 MFMA; squash+uhat fused (fp32) = r19.

#define BSZ 32

typedef unsigned short u16;
using bf16x8 = __attribute__((ext_vector_type(8))) short;
using f16x8 = __attribute__((ext_vector_type(8))) _Float16;
using f32x4 = __attribute__((ext_vector_type(4))) float;

__device__ inline u16 f2bf(float f) {
  union { float f; unsigned u; } v; v.f = f;
  unsigned r = v.u + 0x7FFF + ((v.u >> 16) & 1);
  return (u16)(r >> 16);
}
__device__ inline float bf2f(u16 h) {
  union { unsigned u; float f; } v; v.u = ((unsigned)h) << 16;
  return v.f;
}
__device__ inline u16 f2h(float f) {
  union { _Float16 h; u16 u; } v; v.h = (_Float16)f;
  return v.u;
}
__device__ inline float h2f(u16 b) {
  union { u16 u; _Float16 h; } v; v.u = b;
  return (float)v.h;
}

// ---------------------------------------------------------------- temporal branch: conv1d x3 fused
// one block per batch; x(64,64)->t1(64,64)->t2(128,64) in LDS; t3(256,64) -> global.
__global__ __launch_bounds__(256) void temporal_k(
    const float* __restrict__ x,
    const float* __restrict__ w1, const float* __restrict__ b1,
    const float* __restrict__ w2, const float* __restrict__ b2,
    const float* __restrict__ w3, const float* __restrict__ b3,
    float* __restrict__ t3out) {
  __shared__ float s_in[64 * 64];
  __shared__ float s_t1[64 * 64];
  __shared__ float s_t2[128 * 64];
  const int b = blockIdx.x;
  const int tid = threadIdx.x;
  for (int s = tid; s < 4096; s += 256) s_in[s] = x[(size_t)b * 4096 + s];
  __syncthreads();
  for (int s = tid; s < 4096; s += 256) {
    int co = s >> 6, xx = s & 63;
    float acc = b1[co];
    const float* wp = w1 + (size_t)co * 320;
    for (int ci = 0; ci < 64; ++ci) {
      const float* ir = s_in + ci * 64;
      const float* wr_ = wp + ci * 5;
#pragma unroll
      for (int k = 0; k < 5; ++k) {
        int p = xx + k - 2;
        if (p >= 0 && p < 64) acc += ir[p] * wr_[k];
      }
    }
    s_t1[s] = fmaxf(acc, 0.f);
  }
  __syncthreads();
  for (int s = tid; s < 8192; s += 256) {
    int co = s >> 6, xx = s & 63;
    float acc = b2[co];
    const float* wp = w2 + (size_t)co * 320;
    for (int ci = 0; ci < 64; ++ci) {
      const float* ir = s_t1 + ci * 64;
      const float* wr_ = wp + ci * 5;
#pragma unroll
      for (int k = 0; k < 5; ++k) {
        int p = xx + k - 2;
        if (p >= 0 && p < 64) acc += ir[p] * wr_[k];
      }
    }
    s_t2[s] = fmaxf(acc, 0.f);
  }
  __syncthreads();
  for (int s = tid; s < 16384; s += 256) {
    int co = s >> 6, xx = s & 63;
    float acc = b3[co];
    const float* wp = w3 + (size_t)co * 640;
    for (int ci = 0; ci < 128; ++ci) {
      const float* ir = s_t2 + ci * 64;
      const float* wr_ = wp + ci * 5;
#pragma unroll
      for (int k = 0; k < 5; ++k) {
        int p = xx + k - 2;
        if (p >= 0 && p < 64) acc += ir[p] * wr_[k];
      }
    }
    t3out[(size_t)b * 16384 + s] = fmaxf(acc, 0.f);
  }
}

// ---------------------------------------------------------------- conv2d 3x3 pad=1 + relu (scalar; s1 only)
template <int CI, int CIC>
__global__ __launch_bounds__(256) void conv3x3_relu_k(
    const float* __restrict__ in, const float* __restrict__ w,
    const float* __restrict__ bias, float* __restrict__ out, int CO) {
  __shared__ float in_t[CIC][18][20];
  __shared__ float w_t[CIC][16][12];
  int t = threadIdx.x;
  int co_l = t & 15;
  int g = t >> 4;
  int gy = g >> 2, gx = g & 3;
  int y0 = (blockIdx.x >> 2) * 16, x0 = (blockIdx.x & 3) * 16;
  int co = blockIdx.y * 16 + co_l;
  int b = blockIdx.z;
  float acc[16];
#pragma unroll
  for (int i = 0; i < 16; ++i) acc[i] = 0.f;

  for (int cib = 0; cib < CI / CIC; ++cib) {
    int ci0 = cib * CIC;
    for (int s = t; s < CIC * 324; s += 256) {
      int ci = s / 324;
      int r = s - ci * 324;
      int iy = r / 18, ix = r - iy * 18;
      int gyy = y0 + iy - 1, gxx = x0 + ix - 1;
      float v = 0.f;
      if (gyy >= 0 && gyy < 64 && gxx >= 0 && gxx < 64)
        v = in[((size_t)b * CI + ci0 + ci) * 4096 + gyy * 64 + gxx];
      in_t[ci][iy][ix] = v;
    }
    for (int s = t; s < CIC * 144; s += 256) {
      int ci = s / 144;
      int r = s - ci * 144;
      int cw = r / 9, k = r - cw * 9;
      w_t[ci][cw][k] = w[((size_t)(blockIdx.y * 16 + cw) * CI + ci0 + ci) * 9 + k];
    }
    __syncthreads();
    for (int ci = 0; ci < CIC; ++ci) {
      float wv[9];
#pragma unroll
      for (int k = 0; k < 9; ++k) wv[k] = w_t[ci][co_l][k];
      float pin[36];
#pragma unroll
      for (int r6 = 0; r6 < 6; ++r6)
#pragma unroll
        for (int c6 = 0; c6 < 6; ++c6)
          pin[r6 * 6 + c6] = in_t[ci][4 * gy + r6][4 * gx + c6];
#pragma unroll
      for (int py = 0; py < 4; ++py)
#pragma unroll
        for (int px = 0; px < 4; ++px) {
          float s_ = acc[py * 4 + px];
#pragma unroll
          for (int ky = 0; ky < 3; ++ky)
#pragma unroll
            for (int kx = 0; kx < 3; ++kx)
              s_ += pin[(py + ky) * 6 + (px + kx)] * wv[ky * 3 + kx];
          acc[py * 4 + px] = s_;
        }
    }
    __syncthreads();
  }
  float bv = bias[co];
#pragma unroll
  for (int py = 0; py < 4; ++py)
#pragma unroll
    for (int px = 0; px < 4; ++px)
      out[((size_t)b * CO + co) * 4096 + (size_t)(y0 + 4 * gy + py) * 64 +
          (x0 + 4 * gx + px)] = fmaxf(acc[py * 4 + px] + bv, 0.f);
}

// ---------------------------------------------------------------- w_f -> bf16 [9][256][32] hi/lo (K padded 260->288)
__global__ __launch_bounds__(256) void transpose_wf1_k(const float* __restrict__ wf,
                                                       u16* __restrict__ wh,
                                                       u16* __restrict__ wl) {
  int c = blockIdx.x;  // 0..8
  int co = threadIdx.x;
  u16 th[32], tl[32];
#pragma unroll
  for (int j = 0; j < 32; ++j) {
    int lc = c * 32 + j;
    float f = (lc < 260) ? wf[(size_t)co * 260 + lc] : 0.f;
    u16 h = f2bf(f);
    th[j] = h;
    tl[j] = f2bf(f - bf2f(h));
  }
  ushort4* dh = (ushort4*)(wh + ((size_t)c * 256 + co) * 32);
  ushort4* dl = (ushort4*)(wl + ((size_t)c * 256 + co) * 32);
#pragma unroll
  for (int q = 0; q < 8; ++q) {
    dh[q] = make_ushort4(th[4 * q], th[4 * q + 1], th[4 * q + 2], th[4 * q + 3]);
    dl[q] = make_ushort4(tl[4 * q], tl[4 * q + 1], tl[4 * q + 2], tl[4 * q + 3]);
  }
}

// ---------------------------------------------------------------- w_p -> fp16 WT_hi/WT_lo [g*81+tap][co][ci%32]
__global__ __launch_bounds__(256) void transpose_wp_k(const float* __restrict__ wp,
                                                      u16* __restrict__ wth,
                                                      u16* __restrict__ wtl) {
  int s = blockIdx.x;  // 0..647 = g*81 + tap
  int g = s / 81, t = s - g * 81;
  int co = threadIdx.x;
  u16 th[32], tl[32];
#pragma unroll
  for (int c = 0; c < 32; ++c) {
    float f = wp[((size_t)co * 256 + g * 32 + c) * 81 + t];
    u16 h = f2h(f);
    th[c] = h;
    tl[c] = f2h(f - h2f(h));
  }
  ushort4* dh = (ushort4*)(wth + ((size_t)s * 256 + co) * 32);
  ushort4* dl = (ushort4*)(wtl + ((size_t)s * 256 + co) * 32);
#pragma unroll
  for (int q = 0; q < 8; ++q) {
    dh[q] = make_ushort4(th[4 * q], th[4 * q + 1], th[4 * q + 2], th[4 * q + 3]);
    dl[q] = make_ushort4(tl[4 * q], tl[4 * q + 1], tl[4 * q + 2], tl[4 * q + 3]);
  }
}

// ---------------------------------------------------------------- w3 (CO,CI,3,3) -> bf16 [g*9+tap][co][32] hi/lo
template <int CO, int NCHUNK>
__global__ __launch_bounds__(256) void transpose_w3_k(const float* __restrict__ w,
                                                      u16* __restrict__ wh,
                                                      u16* __restrict__ wl) {
  int tab = blockIdx.x;  // NCHUNK*9
  int g = tab / 9, tap = tab - g * 9;
  int co = threadIdx.x;
  if (co >= CO) return;
  constexpr int CI = NCHUNK * 32;
  u16 th[32], tl[32];
#pragma unroll
  for (int c = 0; c < 32; ++c) {
    float f = w[((size_t)co * CI + g * 32 + c) * 9 + tap];
    u16 h = f2bf(f);
    th[c] = h;
    tl[c] = f2bf(f - bf2f(h));
  }
  ushort4* dh = (ushort4*)(wh + ((size_t)tab * CO + co) * 32);
  ushort4* dl = (ushort4*)(wl + ((size_t)tab * CO + co) * 32);
#pragma unroll
  for (int q = 0; q < 8; ++q) {
    dh[q] = make_ushort4(th[4 * q], th[4 * q + 1], th[4 * q + 2], th[4 * q + 3]);
    dl[q] = make_ushort4(tl[4 * q], tl[4 * q + 1], tl[4 * q + 2], tl[4 * q + 3]);
  }
}

// ---------------------------------------------------------------- conv3x3 pad=1 s=1, MFMA bf16 hi/lo, B->regs
// Round 20: dual-plane A staging -- one global read per chunk fills hi+lo LDS planes;
// 2 barriers/chunk; per tap 3 products {Ah*Bh, Ah*Bl, Al*Bh}.
template <int WMG, int WNG, int NCHUNK, int CO>
__global__ __launch_bounds__(512) void conv3x3_mfma_k(const float* __restrict__ in,
                                                      const u16* __restrict__ Wh,
                                                      const u16* __restrict__ Wl,
                                                      const float* __restrict__ bias,
                                                      float* __restrict__ out) {
  constexpr int CI = NCHUNK * 32;
  constexpr int ROWS = WMG + 2;
  constexpr int APL = ROWS * 66 * 80;
  __shared__ __align__(16) char lds_a[2 * APL];
  const int tid = threadIdx.x;
  const int b = blockIdx.y;
  const int y0 = blockIdx.x * WMG;
  const int w = tid >> 6, l = tid & 63;
  const int wm = w / WNG, wn = w % WNG;
  const int kb = l >> 4, il = l & 15;

  int abase[4];
#pragma unroll
  for (int mb = 0; mb < 4; ++mb) {
    int lp = (wm * 4 + mb) * 16 + il;
    int ly = lp >> 6, lx = lp & 63;
    abase[mb] = (ly * 66 + lx) * 80 + kb * 16;
  }
  int boff[4];
#pragma unroll
  for (int nbi = 0; nbi < 4; ++nbi)
    boff[nbi] = ((wn * 4 + nbi) * 16 + il) * 64 + kb * 16;

  f32x4 acc[4][4];
#pragma unroll
  for (int mb = 0; mb < 4; ++mb)
#pragma unroll
    for (int nbi = 0; nbi < 4; ++nbi) {
      f32x4 z = {0.f, 0.f, 0.f, 0.f};
      acc[mb][nbi] = z;
    }

  const float* Fb = in + (size_t)b * CI * 4096;
  const char* WhB = (const char*)Wh;
  const char* WlB = (const char*)Wl;

  auto stageA2 = [&](int g) {
    const float* src = Fb + (size_t)g * 32 * 4096;
    for (int s = tid; s < ROWS * 66 * 8; s += 512) {
      int ciq = s & 7;
      int rest = s >> 3;
      int r = rest / 66, x = rest - r * 66;
      int row = y0 - 1 + r, col = x - 1;
      float a0 = 0.f, a1 = 0.f, a2 = 0.f, a3 = 0.f;
      if (row >= 0 && row < 64 && col >= 0 && col < 64) {
        const float* p = src + (size_t)(ciq * 4) * 4096 + row * 64 + col;
        a0 = p[0];
        a1 = p[4096];
        a2 = p[8192];
        a3 = p[12288];
      }
      u16 h0 = f2bf(a0), h1 = f2bf(a1), h2 = f2bf(a2), h3 = f2bf(a3);
      u16 l0 = f2bf(a0 - bf2f(h0)), l1 = f2bf(a1 - bf2f(h1));
      u16 l2 = f2bf(a2 - bf2f(h2)), l3 = f2bf(a3 - bf2f(h3));
      int off = (r * 66 + x) * 80 + ciq * 8;
      *(ushort4*)(lds_a + off) = make_ushort4(h0, h1, h2, h3);
      *(ushort4*)(lds_a + APL + off) = make_ushort4(l0, l1, l2, l3);
    }
  };

  for (int g = 0; g < NCHUNK; ++g) {
    __syncthreads();
    stageA2(g);
    __syncthreads();
#pragma unroll
    for (int tap = 0; tap < 9; ++tap) {
      const char* pb = WhB + (size_t)(g * 9 + tap) * (CO * 64);
      const char* pl = WlB + (size_t)(g * 9 + tap) * (CO * 64);
      bf16x8 bh[4], bl[4];
#pragma unroll
      for (int nbi = 0; nbi < 4; ++nbi) {
        bh[nbi] = *(const bf16x8*)(pb + boff[nbi]);
        bl[nbi] = *(const bf16x8*)(pl + boff[nbi]);
      }
      int ky = tap / 3, kx = tap - ky * 3;
      int toff = (ky * 66 + kx) * 80;
      bf16x8 avh[4], avl[4];
#pragma unroll
      for (int mb = 0; mb < 4; ++mb) {
        avh[mb] = *(const bf16x8*)(lds_a + abase[mb] + toff);
        avl[mb] = *(const bf16x8*)(lds_a + APL + abase[mb] + toff);
      }
#pragma unroll
      for (int mb = 0; mb < 4; ++mb)
#pragma unroll
        for (int nbi = 0; nbi < 4; ++nbi) {
          acc[mb][nbi] = __builtin_amdgcn_mfma_f32_16x16x32_bf16(
              avh[mb], bh[nbi], acc[mb][nbi], 0, 0, 0);
          acc[mb][nbi] = __builtin_amdgcn_mfma_f32_16x16x32_bf16(
              avh[mb], bl[nbi], acc[mb][nbi], 0, 0, 0);
          acc[mb][nbi] = __builtin_amdgcn_mfma_f32_16x16x32_bf16(
              avl[mb], bh[nbi], acc[mb][nbi], 0, 0, 0);
        }
    }
  }

  const int p0 = y0 * 64;
#pragma unroll
  for (int mb = 0; mb < 4; ++mb) {
    int pixb = p0 + (wm * 4 + mb) * 16 + kb * 4;
#pragma unroll
    for (int nbi = 0; nbi < 4; ++nbi) {
      int co = (wn * 4 + nbi) * 16 + il;
      float bv_ = bias[co];
      f32x4 a = acc[mb][nbi];
      float4 o = make_float4(fmaxf(a[0] + bv_, 0.f), fmaxf(a[1] + bv_, 0.f),
                             fmaxf(a[2] + bv_, 0.f), fmaxf(a[3] + bv_, 0.f));
      *(float4*)(out + (size_t)(b * CO + co) * 4096 + pixb) = o;
    }
  }
}

// ---------------------------------------------------------------- 1x1 fusion via MFMA bf16 hi/lo (exact)
// (round-17 version)
__global__ __launch_bounds__(512) void fuse_mfma_k(const float* __restrict__ t3,
                                                   const u16* __restrict__ Wh,
                                                   const u16* __restrict__ Wl,
                                                   const float* __restrict__ bf,
                                                   float* __restrict__ a) {
  constexpr int APL = 128 * 80;
  __shared__ __align__(16) char lds_a[2 * APL];
  const int tid = threadIdx.x;
  const int b = blockIdx.y;
  const int p0 = blockIdx.x * 128;
  const int w = tid >> 6, l = tid & 63;
  const int wm = w >> 2, wn = w & 3;
  const int kb = l >> 4, il = l & 15;

  int abase[4];
#pragma unroll
  for (int mb = 0; mb < 4; ++mb)
    abase[mb] = ((wm * 4 + mb) * 16 + il) * 80 + kb * 16;
  int boff[4];
#pragma unroll
  for (int nbi = 0; nbi < 4; ++nbi)
    boff[nbi] = ((wn * 4 + nbi) * 16 + il) * 64 + kb * 16;

  f32x4 acc[4][4];
#pragma unroll
  for (int mb = 0; mb < 4; ++mb)
#pragma unroll
    for (int nbi = 0; nbi < 4; ++nbi) {
      f32x4 z = {0.f, 0.f, 0.f, 0.f};
      acc[mb][nbi] = z;
    }

  const char* WhB = (const char*)Wh;
  const char* WlB = (const char*)Wl;

  auto stageAB = [&](int c) {
    for (int s = tid; s < 128 * 8; s += 512) {
      int ciq = s & 7, px = s >> 3;
      int pg = p0 + px;
      u16 eh[4], el[4];
#pragma unroll
      for (int q = 0; q < 4; ++q) {
        int lc = c * 32 + ciq * 4 + q;
        float f = 0.f;
        if (lc < 4)
          f = t3[(size_t)b * 16384 + lc * 4096 + pg];
        else if (lc < 260)
          f = a[((size_t)b * 256 + (lc - 4)) * 4096 + pg];
        u16 h = f2bf(f);
        eh[q] = h;
        el[q] = f2bf(f - bf2f(h));
      }
      *(ushort4*)(lds_a + px * 80 + ciq * 8) = make_ushort4(eh[0], eh[1], eh[2], eh[3]);
      *(ushort4*)(lds_a + APL + px * 80 + ciq * 8) =
          make_ushort4(el[0], el[1], el[2], el[3]);
    }
  };

  for (int c = 0; c < 9; ++c) {
    __syncthreads();
    stageAB(c);
    __syncthreads();
    bf16x8 bh[4], bl[4];
#pragma unroll
    for (int nbi = 0; nbi < 4; ++nbi) {
      bh[nbi] = *(const bf16x8*)(WhB + (size_t)c * 16384 + boff[nbi]);
      bl[nbi] = *(const bf16x8*)(WlB + (size_t)c * 16384 + boff[nbi]);
    }
    bf16x8 avh[4], avl[4];
#pragma unroll
    for (int mb = 0; mb < 4; ++mb) {
      avh[mb] = *(const bf16x8*)(lds_a + abase[mb]);
      avl[mb] = *(const bf16x8*)(lds_a + APL + abase[mb]);
    }
#pragma unroll
    for (int mb = 0; mb < 4; ++mb)
#pragma unroll
      for (int nbi = 0; nbi < 4; ++nbi) {
        acc[mb][nbi] = __builtin_amdgcn_mfma_f32_16x16x32_bf16(
            avh[mb], bh[nbi], acc[mb][nbi], 0, 0, 0);
        acc[mb][nbi] = __builtin_amdgcn_mfma_f32_16x16x32_bf16(
            avh[mb], bl[nbi], acc[mb][nbi], 0, 0, 0);
        acc[mb][nbi] = __builtin_amdgcn_mfma_f32_16x16x32_bf16(
            avl[mb], bh[nbi], acc[mb][nbi], 0, 0, 0);
      }
  }

#pragma unroll
  for (int mb = 0; mb < 4; ++mb) {
    int pixb = p0 + (wm * 4 + mb) * 16 + kb * 4;
#pragma unroll
    for (int nbi = 0; nbi < 4; ++nbi) {
      int co = (wn * 4 + nbi) * 16 + il;
      float bv_ = bf[co];
      f32x4 v = acc[mb][nbi];
      float4 o = make_float4(v[0] + bv_, v[1] + bv_, v[2] + bv_, v[3] + bv_);
      *(float4*)(a + (size_t)(b * 256 + co) * 4096 + pixb) = o;
    }
  }
}

// ---------------------------------------------------------------- 9x9 s2 conv, MFMA fp16 2-pass, 16 waves
// (round-15 version, unchanged)
__global__ __launch_bounds__(1024) void conv9x9_mfma_k(const float* __restrict__ fused,
                                                       const u16* __restrict__ WTh,
                                                       const u16* __restrict__ WTl,
                                                       const float* __restrict__ bias,
                                                       float* __restrict__ praw) {
  constexpr int APLANE = 19 * 32 * 80;
  __shared__ __align__(16) char lds_a[2 * APLANE];
  const int tid = threadIdx.x;
  const int b = blockIdx.y, tile = blockIdx.x;
  const int p0 = tile * 128;
  const int oy0 = p0 / 28;
  const int w = tid >> 6, l = tid & 63;
  const int wm = w >> 3, wn = w & 7;
  const int kb = l >> 4, il = l & 15;

  int abase[4];
#pragma unroll
  for (int mb = 0; mb < 4; ++mb) {
    int p = p0 + (wm * 4 + mb) * 16 + il;
    int oy = p / 28, ox = p - oy * 28;
    abase[mb] = (2 * (oy - oy0)) * 2560 + ox * 80 + kb * 16;
  }
  int boff[2];
#pragma unroll
  for (int nbi = 0; nbi < 2; ++nbi)
    boff[nbi] = (wn * 32 + nbi * 16 + il) * 64 + kb * 16;

  f32x4 acc[4][2];
#pragma unroll
  for (int mb = 0; mb < 4; ++mb)
#pragma unroll
    for (int nbi = 0; nbi < 2; ++nbi) {
      f32x4 z = {0.f, 0.f, 0.f, 0.f};
      acc[mb][nbi] = z;
    }

  const float* Fb = fused + (size_t)b * 256 * 4096;
  const char* WhB = (const char*)WTh;
  const char* WlB = (const char*)WTl;

  auto stageA = [&](int g) {
    const float* src = Fb + (size_t)g * 32 * 4096;
    for (int s = tid; s < 19 * 63 * 8; s += 1024) {
      int ciq = s / 1197;
      int rem = s - ciq * 1197;
      int r = rem / 63, t63 = rem - r * 63;
      int x2 = (t63 < 32) ? 2 * t63 : 2 * (t63 - 32) + 1;
      int iy = 2 * oy0 + r;
      float a0 = 0.f, a1 = 0.f, a2 = 0.f, a3 = 0.f;
      if (iy < 64) {
        const float* pp0 = src + (size_t)(ciq * 4) * 4096 + iy * 64 + x2;
        a0 = pp0[0];
        a1 = pp0[4096];
        a2 = pp0[8192];
        a3 = pp0[12288];
      }
      u16 e0 = f2h(a0), e1 = f2h(a1), e2 = f2h(a2), e3 = f2h(a3);
      int off = (x2 & 1) * APLANE + (r * 32 + (x2 >> 1)) * 80 + ciq * 8;
      *(ushort4*)(lds_a + off) = make_ushort4(e0, e1, e2, e3);
    }
  };

  for (int g = 0; g < 8; ++g) {
    __syncthreads();
    stageA(g);
    __syncthreads();
#pragma unroll 3
    for (int t = 0; t < 81; ++t) {
      const char* pb = WhB + (size_t)(g * 81 + t) * 16384;
      const char* pl = WlB + (size_t)(g * 81 + t) * 16384;
      f16x8 bh[2], bl[2];
#pragma unroll
      for (int nbi = 0; nbi < 2; ++nbi) {
        bh[nbi] = *(const f16x8*)(pb + boff[nbi]);
        bl[nbi] = *(const f16x8*)(pl + boff[nbi]);
      }
      int ky = t / 9, kx = t - ky * 9;
      int toff = (kx & 1) * APLANE + ky * 2560 + (kx >> 1) * 80;
      f16x8 av[4];
#pragma unroll
      for (int mb = 0; mb < 4; ++mb)
        av[mb] = *(const f16x8*)(lds_a + abase[mb] + toff);
#pragma unroll
      for (int mb = 0; mb < 4; ++mb)
#pragma unroll
        for (int nbi = 0; nbi < 2; ++nbi) {
          acc[mb][nbi] = __builtin_amdgcn_mfma_f32_16x16x32_f16(
              av[mb], bh[nbi], acc[mb][nbi], 0, 0, 0);
          acc[mb][nbi] = __builtin_amdgcn_mfma_f32_16x16x32_f16(
              av[mb], bl[nbi], acc[mb][nbi], 0, 0, 0);
        }
    }
  }

#pragma unroll
  for (int mb = 0; mb < 4; ++mb) {
    int pixb = p0 + (wm * 4 + mb) * 16 + kb * 4;
    if (pixb < 784) {
#pragma unroll
      for (int nbi = 0; nbi < 2; ++nbi) {
        int co = wn * 32 + nbi * 16 + il;
        float bv_ = bias[co];
        f32x4 v = acc[mb][nbi];
        float4 o = make_float4(v[0] + bv_, v[1] + bv_, v[2] + bv_, v[3] + bv_);
        *(float4*)(praw + (size_t)(b * 256 + co) * 784 + pixb) = o;
      }
    }
  }
}

// ---------------------------------------------------------------- fused squash + u_hat (fp32 out)
__global__ __launch_bounds__(256) void squash_uhat_k(const float* __restrict__ praw,
                                                     const float* __restrict__ w_r,
                                                     float* __restrict__ u_hat) {
  int i = blockIdx.x * 256 + threadIdx.x;  // 25088
  int b = blockIdx.y;
  int prim = i / 784, pix = i - prim * 784;
  const float* pp = praw + ((size_t)b * 256 + prim * 8) * 784 + pix;
  float xv[8];
  float sn = 0.f;
#pragma unroll
  for (int d = 0; d < 8; ++d) {
    xv[d] = pp[(size_t)d * 784];
    sn += xv[d] * xv[d];
  }
  float scale = sn / ((1.f + sn) * sqrtf(sn + 1e-8f));
  float4 ua = make_float4(xv[0] * scale, xv[1] * scale, xv[2] * scale, xv[3] * scale);
  float4 ub = make_float4(xv[4] * scale, xv[5] * scale, xv[6] * scale, xv[7] * scale);

  const float4* wr = (const float4*)(w_r + (size_t)i * 256);
  float res[32];
#pragma unroll
  for (int od = 0; od < 32; ++od) {
    float4 wa = wr[od * 2], wb = wr[od * 2 + 1];
    res[od] = wa.x * ua.x + wa.y * ua.y + wa.z * ua.z + wa.w * ua.w +
              wb.x * ub.x + wb.y * ub.y + wb.z * ub.z + wb.w * ub.w;
  }
  float4* dst = (float4*)(u_hat + ((size_t)b * 25088 + i) * 32);
#pragma unroll
  for (int q = 0; q < 8; ++q)
    dst[q] = make_float4(res[4 * q], res[4 * q + 1], res[4 * q + 2], res[4 * q + 3]);
}

// ---------------------------------------------------------------- routing iter0: s_j partials (c = 0.5)
__global__ __launch_bounds__(256) void route_sj_k(const float* __restrict__ u_hat,
                                                  float* __restrict__ sj_part) {
  int b = blockIdx.x;
  int seg = blockIdx.y;
  int t = threadIdx.x;
  float acc[32];
#pragma unroll
  for (int j = 0; j < 32; ++j) acc[j] = 0.f;
  int i0 = seg * 3136;
  for (int i = i0 + t; i < i0 + 3136; i += 256) {
    const float4* uh = (const float4*)(u_hat + ((size_t)b * 25088 + i) * 32);
#pragma unroll
    for (int q = 0; q < 4; ++q) {
      float4 va = uh[q];
      acc[4 * q + 0] += 0.5f * va.x;
      acc[4 * q + 1] += 0.5f * va.y;
      acc[4 * q + 2] += 0.5f * va.z;
      acc[4 * q + 3] += 0.5f * va.w;
      float4 vb = uh[4 + q];
      acc[16 + 4 * q + 0] += 0.5f * vb.x;
      acc[16 + 4 * q + 1] += 0.5f * vb.y;
      acc[16 + 4 * q + 2] += 0.5f * vb.z;
      acc[16 + 4 * q + 3] += 0.5f * vb.w;
    }
  }
#pragma unroll
  for (int j = 0; j < 32; ++j) {
    acc[j] += __shfl_down(acc[j], 32);
    acc[j] += __shfl_down(acc[j], 16);
    acc[j] += __shfl_down(acc[j], 8);
    acc[j] += __shfl_down(acc[j], 4);
    acc[j] += __shfl_down(acc[j], 2);
    acc[j] += __shfl_down(acc[j], 1);
  }
  __shared__ float red[4][32];
  int wave = t >> 6, lane = t & 63;
  if (lane == 0) {
#pragma unroll
    for (int j = 0; j < 32; ++j) red[wave][j] = acc[j];
  }
  __syncthreads();
  if (t < 32) {
    float s = red[0][t] + red[1][t] + red[2][t] + red[3][t];
    sj_part[((size_t)b * 8 + seg) * 32 + t] = s;
  }
}

// ---------------------------------------------------------------- routing fused v+upd+sj (iters 1,2)
// prologue: compute v[32] from sjp_in (8 segs); then e = u_hat.v, b_ij update,
// softmax, accumulate s_j partials -> sjp_out (ping-pong buffer).
__global__ __launch_bounds__(256) void route_fsj_k(const float* __restrict__ u_hat,
                                                   const float* __restrict__ sjp_in,
                                                   float* __restrict__ b_ij,
                                                   float* __restrict__ sjp_out, int first) {
  int b = blockIdx.x;
  int seg = blockIdx.y;
  int t = threadIdx.x;
  __shared__ float vsh[32];
  if (t < 32) {
    float s = 0.f;
#pragma unroll
    for (int sg = 0; sg < 8; ++sg) s += sjp_in[((size_t)b * 8 + sg) * 32 + t];
    float sn = s * s;
    vsh[t] = sn * s / ((1.f + sn) * sqrtf(sn + 1e-8f));
  }
  __syncthreads();
  float vp[32];
#pragma unroll
  for (int j = 0; j < 32; ++j) vp[j] = vsh[j];

  float acc[32];
#pragma unroll
  for (int j = 0; j < 32; ++j) acc[j] = 0.f;
  int i0 = seg * 3136;
  for (int i = i0 + t; i < i0 + 3136; i += 256) {
    const float4* uhp = (const float4*)(u_hat + ((size_t)b * 25088 + i) * 32);
    float4 uh[8];
#pragma unroll
    for (int q = 0; q < 8; ++q) uh[q] = uhp[q];
    float e0 = 0.f, e1 = 0.f;
#pragma unroll
    for (int q = 0; q < 4; ++q) {
      e0 += uh[q].x * vp[4 * q] + uh[q].y * vp[4 * q + 1] + uh[q].z * vp[4 * q + 2] +
            uh[q].w * vp[4 * q + 3];
      e1 += uh[4 + q].x * vp[16 + 4 * q] + uh[4 + q].y * vp[16 + 4 * q + 1] +
            uh[4 + q].z * vp[16 + 4 * q + 2] + uh[4 + q].w * vp[16 + 4 * q + 3];
    }
    size_t o = ((size_t)b * 25088 + i) * 2;
    float b0, b1;
    if (first) {
      b0 = e0;
      b1 = e1;
      b_ij[o + 0] = e0;
      b_ij[o + 1] = e1;
    } else {
      b0 = b_ij[o + 0] + e0;
      b1 = b_ij[o + 1] + e1;
    }
    float m = fmaxf(b0, b1);
    float x0 = expf(b0 - m), x1 = expf(b1 - m);
    float inv = 1.f / (x0 + x1);
    float c0 = x0 * inv, c1 = x1 * inv;
#pragma unroll
    for (int q = 0; q < 4; ++q) {
      acc[4 * q + 0] += c0 * uh[q].x;
      acc[4 * q + 1] += c0 * uh[q].y;
      acc[4 * q + 2] += c0 * uh[q].z;
      acc[4 * q + 3] += c0 * uh[q].w;
      acc[16 + 4 * q + 0] += c1 * uh[4 + q].x;
      acc[16 + 4 * q + 1] += c1 * uh[4 + q].y;
      acc[16 + 4 * q + 2] += c1 * uh[4 + q].z;
      acc[16 + 4 * q + 3] += c1 * uh[4 + q].w;
    }
  }
#pragma unroll
  for (int j = 0; j < 32; ++j) {
    acc[j] += __shfl_down(acc[j], 32);
    acc[j] += __shfl_down(acc[j], 16);
    acc[j] += __shfl_down(acc[j], 8);
    acc[j] += __shfl_down(acc[j], 4);
    acc[j] += __shfl_down(acc[j], 2);
    acc[j] += __shfl_down(acc[j], 1);
  }
  __shared__ float red[4][32];
  int wave = t >> 6, lane = t & 63;
  if (lane == 0) {
#pragma unroll
    for (int j = 0; j < 32; ++j) red[wave][j] = acc[j];
  }
  __syncthreads();
  if (t < 32) {
    float s = red[0][t] + red[1][t] + red[2][t] + red[3][t];
    sjp_out[((size_t)b * 8 + seg) * 32 + t] = s;
  }
}

// ---------------------------------------------------------------- routing: finalize v -> out
__global__ __launch_bounds__(256) void route_fin_k(const float* __restrict__ sj_part,
                                                   float* __restrict__ v,
                                                   float* __restrict__ out, int final_it) {
  int idx = blockIdx.x * 256 + threadIdx.x;
  if (idx >= BSZ * 32) return;
  int b = idx >> 5, j = idx & 31;
  float s = 0.f;
#pragma unroll
  for (int seg = 0; seg < 8; ++seg) s += sj_part[((size_t)b * 8 + seg) * 32 + j];
  float sn = s * s;
  float vv = sn * s / ((1.f + sn) * sqrtf(sn + 1e-8f));
  v[idx] = vv;
  if (final_it) out[idx] = fabsf(vv);
}

// ================================================================ launch
extern "C" void kernel_launch(void* const* d_in, const int* in_sizes, int n_in,
                              void* d_out, int out_size, void* d_ws, size_t ws_size,
                              hipStream_t stream) {
  (void)in_sizes; (void)n_in; (void)out_size;
  const float* x    = (const float*)d_in[0];
  const float* w_t1 = (const float*)d_in[1];
  const float* b_t1 = (const float*)d_in[2];
  const float* w_t2 = (const float*)d_in[3];
  const float* b_t2 = (const float*)d_in[4];
  const float* w_t3 = (const float*)d_in[5];
  const float* b_t3 = (const float*)d_in[6];
  const float* w_s1 = (const float*)d_in[7];
  const float* b_s1 = (const float*)d_in[8];
  const float* w_s2 = (const float*)d_in[9];
  const float* b_s2 = (const float*)d_in[10];
  const float* w_s3 = (const float*)d_in[11];
  const float* b_s3 = (const float*)d_in[12];
  const float* w_f  = (const float*)d_in[13];
  const float* b_f  = (const float*)d_in[14];
  const float* w_p  = (const float*)d_in[15];
  const float* b_p  = (const float*)d_in[16];
  const float* w_r  = (const float*)d_in[17];
  float* out = (float*)d_out;

  char* ws = (char*)d_ws;
  if (ws_size < 238854144ull) return;
  // region 0: fused (fp32) -> uhat (fp32, 102.8MB)
  float* fused = (float*)(ws + 0);
  float* uhat  = (float*)(ws + 0);
  // region 1 (134,217,728): s2q -> praw / b_ij
  float* s2q   = (float*)(ws + 134217728);
  float* praw  = (float*)(ws + 134217728);
  float* b_ij  = (float*)(ws + 185597952);
  // region 2 (201,326,592): s1 -> t3/wTh/wTl
  float* s1    = (float*)(ws + 201326592);
  float* t3    = (float*)(ws + 202899456);
  u16*   wTh   = (u16*)  (ws + 204996608);
  u16*   wTl   = (u16*)  (ws + 215613440);
  // tail (234,881,024): persistent small tables
  u16*   w3a_h = (u16*)  (ws + 234881024);
  u16*   w3a_l = (u16*)  (ws + 235028480);
  u16*   w3b_h = (u16*)  (ws + 235175936);
  u16*   w3b_l = (u16*)  (ws + 235765760);
  u16*   wf1_h = (u16*)  (ws + 236355584);
  u16*   wf1_l = (u16*)  (ws + 236503040);
  float* sjpA  = (float*)(ws + 236650496);
  float* sjpB  = (float*)(ws + 236683264);
  float* vbuf  = (float*)(ws + 236716032);

  // small weight tables (tail region -- never clobbered)
  transpose_w3_k<128, 2><<<18, 256, 0, stream>>>(w_s2, w3a_h, w3a_l);
  transpose_w3_k<256, 4><<<36, 256, 0, stream>>>(w_s3, w3b_h, w3b_l);
  transpose_wf1_k<<<9, 256, 0, stream>>>(w_f, wf1_h, wf1_l);

  // spectral: s1 scalar conv, then s2 MFMA conv (consumes s1)
  conv3x3_relu_k<1, 1><<<dim3(16, 4, BSZ), 256, 0, stream>>>(x, w_s1, b_s1, s1, 64);
  conv3x3_mfma_k<4, 2, 2, 128><<<dim3(16, BSZ), 512, 0, stream>>>(s1, w3a_h, w3a_l, b_s2, s2q);

  // s1 now dead: temporal branch (fused) + 9x9 weight tables into its region
  temporal_k<<<BSZ, 256, 0, stream>>>(x, w_t1, b_t1, w_t2, b_t2, w_t3, b_t3, t3);
  transpose_wp_k<<<648, 256, 0, stream>>>(w_p, wTh, wTl);

  // s3 MFMA conv -> fused
  conv3x3_mfma_k<2, 4, 4, 256><<<dim3(32, BSZ), 512, 0, stream>>>(s2q, w3b_h, w3b_l, b_s3, fused);

  // fusion via MFMA, in-place on fused (exact bf16 hi/lo)
  fuse_mfma_k<<<dim3(32, BSZ), 512, 0, stream>>>(t3, wf1_h, wf1_l, b_f, fused);

  // primary capsules via MFMA fp16 2-pass, 16 waves (praw over dead s2q)
  conv9x9_mfma_k<<<dim3(7, BSZ), 1024, 0, stream>>>(fused, wTh, wTl, b_p, praw);

  // fused squash + u_hat (fp32; overwrites fused region)
  squash_uhat_k<<<dim3(98, BSZ), 256, 0, stream>>>(praw, w_r, uhat);

  // dynamic routing, 3 iterations (v computed inline in fsj; sjp ping-pong)
  route_sj_k<<<dim3(BSZ, 8), 256, 0, stream>>>(uhat, sjpA);
  route_fsj_k<<<dim3(BSZ, 8), 256, 0, stream>>>(uhat, sjpA, b_ij, sjpB, 1);
  route_fsj_k<<<dim3(BSZ, 8), 256, 0, stream>>>(uhat, sjpB, b_ij, sjpA, 0);
  route_fin_k<<<4, 256, 0, stream>>>(sjpA, vbuf, out, 1);
}

// Round 21
// 1441.242 us; speedup vs baseline: 3.4989x; 3.4989x over previous
//
#include <hip/hip_runtime.h>
#include <math.h>

// STCCapsNet forward. B=32, C=1, H=W=64, HP=WP=28, IN_CAPS=25088, OUT 32x2x16.
// Round 21: r20 with temporal_k REVERTED to the three conv1d kernels (r20's fused
// temporal had grid=32 -> 1.5% occupancy, 3.6ms). Keeps r20's dual-plane conv3x3
// staging and the route_fin-folded routing (sjp ping-pong).

#define BSZ 32

typedef unsigned short u16;
using bf16x8 = __attribute__((ext_vector_type(8))) short;
using f16x8 = __attribute__((ext_vector_type(8))) _Float16;
using f32x4 = __attribute__((ext_vector_type(4))) float;

__device__ inline u16 f2bf(float f) {
  union { float f; unsigned u; } v; v.f = f;
  unsigned r = v.u + 0x7FFF + ((v.u >> 16) & 1);
  return (u16)(r >> 16);
}
__device__ inline float bf2f(u16 h) {
  union { unsigned u; float f; } v; v.u = ((unsigned)h) << 16;
  return v.f;
}
__device__ inline u16 f2h(float f) {
  union { _Float16 h; u16 u; } v; v.h = (_Float16)f;
  return v.u;
}
__device__ inline float h2f(u16 b) {
  union { u16 u; _Float16 h; } v; v.u = b;
  return (float)v.h;
}

// ---------------------------------------------------------------- conv1d k=5 pad=2 + relu
__global__ __launch_bounds__(256) void conv1d_relu_k(
    const float* __restrict__ in, const float* __restrict__ w,
    const float* __restrict__ bias, float* __restrict__ out, int CI, int CO) {
  int idx = blockIdx.x * 256 + threadIdx.x;
  int total = BSZ * CO * 64;
  if (idx >= total) return;
  int x = idx & 63;
  int co = (idx >> 6) % CO;
  int b = idx / (64 * CO);
  const float* ip = in + (size_t)b * CI * 64;
  const float* wp = w + (size_t)co * CI * 5;
  float acc = bias[co];
  for (int ci = 0; ci < CI; ++ci) {
    const float* ir = ip + ci * 64;
    const float* wr_ = wp + ci * 5;
#pragma unroll
    for (int k = 0; k < 5; ++k) {
      int xx = x + k - 2;
      if (xx >= 0 && xx < 64) acc += ir[xx] * wr_[k];
    }
  }
  out[idx] = fmaxf(acc, 0.f);
}

// ---------------------------------------------------------------- conv2d 3x3 pad=1 + relu (scalar; s1 only)
template <int CI, int CIC>
__global__ __launch_bounds__(256) void conv3x3_relu_k(
    const float* __restrict__ in, const float* __restrict__ w,
    const float* __restrict__ bias, float* __restrict__ out, int CO) {
  __shared__ float in_t[CIC][18][20];
  __shared__ float w_t[CIC][16][12];
  int t = threadIdx.x;
  int co_l = t & 15;
  int g = t >> 4;
  int gy = g >> 2, gx = g & 3;
  int y0 = (blockIdx.x >> 2) * 16, x0 = (blockIdx.x & 3) * 16;
  int co = blockIdx.y * 16 + co_l;
  int b = blockIdx.z;
  float acc[16];
#pragma unroll
  for (int i = 0; i < 16; ++i) acc[i] = 0.f;

  for (int cib = 0; cib < CI / CIC; ++cib) {
    int ci0 = cib * CIC;
    for (int s = t; s < CIC * 324; s += 256) {
      int ci = s / 324;
      int r = s - ci * 324;
      int iy = r / 18, ix = r - iy * 18;
      int gyy = y0 + iy - 1, gxx = x0 + ix - 1;
      float v = 0.f;
      if (gyy >= 0 && gyy < 64 && gxx >= 0 && gxx < 64)
        v = in[((size_t)b * CI + ci0 + ci) * 4096 + gyy * 64 + gxx];
      in_t[ci][iy][ix] = v;
    }
    for (int s = t; s < CIC * 144; s += 256) {
      int ci = s / 144;
      int r = s - ci * 144;
      int cw = r / 9, k = r - cw * 9;
      w_t[ci][cw][k] = w[((size_t)(blockIdx.y * 16 + cw) * CI + ci0 + ci) * 9 + k];
    }
    __syncthreads();
    for (int ci = 0; ci < CIC; ++ci) {
      float wv[9];
#pragma unroll
      for (int k = 0; k < 9; ++k) wv[k] = w_t[ci][co_l][k];
      float pin[36];
#pragma unroll
      for (int r6 = 0; r6 < 6; ++r6)
#pragma unroll
        for (int c6 = 0; c6 < 6; ++c6)
          pin[r6 * 6 + c6] = in_t[ci][4 * gy + r6][4 * gx + c6];
#pragma unroll
      for (int py = 0; py < 4; ++py)
#pragma unroll
        for (int px = 0; px < 4; ++px) {
          float s_ = acc[py * 4 + px];
#pragma unroll
          for (int ky = 0; ky < 3; ++ky)
#pragma unroll
            for (int kx = 0; kx < 3; ++kx)
              s_ += pin[(py + ky) * 6 + (px + kx)] * wv[ky * 3 + kx];
          acc[py * 4 + px] = s_;
        }
    }
    __syncthreads();
  }
  float bv = bias[co];
#pragma unroll
  for (int py = 0; py < 4; ++py)
#pragma unroll
    for (int px = 0; px < 4; ++px)
      out[((size_t)b * CO + co) * 4096 + (size_t)(y0 + 4 * gy + py) * 64 +
          (x0 + 4 * gx + px)] = fmaxf(acc[py * 4 + px] + bv, 0.f);
}

// ---------------------------------------------------------------- w_f -> bf16 [9][256][32] hi/lo (K padded 260->288)
__global__ __launch_bounds__(256) void transpose_wf1_k(const float* __restrict__ wf,
                                                       u16* __restrict__ wh,
                                                       u16* __restrict__ wl) {
  int c = blockIdx.x;  // 0..8
  int co = threadIdx.x;
  u16 th[32], tl[32];
#pragma unroll
  for (int j = 0; j < 32; ++j) {
    int lc = c * 32 + j;
    float f = (lc < 260) ? wf[(size_t)co * 260 + lc] : 0.f;
    u16 h = f2bf(f);
    th[j] = h;
    tl[j] = f2bf(f - bf2f(h));
  }
  ushort4* dh = (ushort4*)(wh + ((size_t)c * 256 + co) * 32);
  ushort4* dl = (ushort4*)(wl + ((size_t)c * 256 + co) * 32);
#pragma unroll
  for (int q = 0; q < 8; ++q) {
    dh[q] = make_ushort4(th[4 * q], th[4 * q + 1], th[4 * q + 2], th[4 * q + 3]);
    dl[q] = make_ushort4(tl[4 * q], tl[4 * q + 1], tl[4 * q + 2], tl[4 * q + 3]);
  }
}

// ---------------------------------------------------------------- w_p -> fp16 WT_hi/WT_lo [g*81+tap][co][ci%32]
__global__ __launch_bounds__(256) void transpose_wp_k(const float* __restrict__ wp,
                                                      u16* __restrict__ wth,
                                                      u16* __restrict__ wtl) {
  int s = blockIdx.x;  // 0..647 = g*81 + tap
  int g = s / 81, t = s - g * 81;
  int co = threadIdx.x;
  u16 th[32], tl[32];
#pragma unroll
  for (int c = 0; c < 32; ++c) {
    float f = wp[((size_t)co * 256 + g * 32 + c) * 81 + t];
    u16 h = f2h(f);
    th[c] = h;
    tl[c] = f2h(f - h2f(h));
  }
  ushort4* dh = (ushort4*)(wth + ((size_t)s * 256 + co) * 32);
  ushort4* dl = (ushort4*)(wtl + ((size_t)s * 256 + co) * 32);
#pragma unroll
  for (int q = 0; q < 8; ++q) {
    dh[q] = make_ushort4(th[4 * q], th[4 * q + 1], th[4 * q + 2], th[4 * q + 3]);
    dl[q] = make_ushort4(tl[4 * q], tl[4 * q + 1], tl[4 * q + 2], tl[4 * q + 3]);
  }
}

// ---------------------------------------------------------------- w3 (CO,CI,3,3) -> bf16 [g*9+tap][co][32] hi/lo
template <int CO, int NCHUNK>
__global__ __launch_bounds__(256) void transpose_w3_k(const float* __restrict__ w,
                                                      u16* __restrict__ wh,
                                                      u16* __restrict__ wl) {
  int tab = blockIdx.x;  // NCHUNK*9
  int g = tab / 9, tap = tab - g * 9;
  int co = threadIdx.x;
  if (co >= CO) return;
  constexpr int CI = NCHUNK * 32;
  u16 th[32], tl[32];
#pragma unroll
  for (int c = 0; c < 32; ++c) {
    float f = w[((size_t)co * CI + g * 32 + c) * 9 + tap];
    u16 h = f2bf(f);
    th[c] = h;
    tl[c] = f2bf(f - bf2f(h));
  }
  ushort4* dh = (ushort4*)(wh + ((size_t)tab * CO + co) * 32);
  ushort4* dl = (ushort4*)(wl + ((size_t)tab * CO + co) * 32);
#pragma unroll
  for (int q = 0; q < 8; ++q) {
    dh[q] = make_ushort4(th[4 * q], th[4 * q + 1], th[4 * q + 2], th[4 * q + 3]);
    dl[q] = make_ushort4(tl[4 * q], tl[4 * q + 1], tl[4 * q + 2], tl[4 * q + 3]);
  }
}

// ---------------------------------------------------------------- conv3x3 pad=1 s=1, MFMA bf16 hi/lo, B->regs
// dual-plane A staging: one global read per chunk fills hi+lo LDS planes; 2 barriers/chunk.
template <int WMG, int WNG, int NCHUNK, int CO>
__global__ __launch_bounds__(512) void conv3x3_mfma_k(const float* __restrict__ in,
                                                      const u16* __restrict__ Wh,
                                                      const u16* __restrict__ Wl,
                                                      const float* __restrict__ bias,
                                                      float* __restrict__ out) {
  constexpr int CI = NCHUNK * 32;
  constexpr int ROWS = WMG + 2;
  constexpr int APL = ROWS * 66 * 80;
  __shared__ __align__(16) char lds_a[2 * APL];
  const int tid = threadIdx.x;
  const int b = blockIdx.y;
  const int y0 = blockIdx.x * WMG;
  const int w = tid >> 6, l = tid & 63;
  const int wm = w / WNG, wn = w % WNG;
  const int kb = l >> 4, il = l & 15;

  int abase[4];
#pragma unroll
  for (int mb = 0; mb < 4; ++mb) {
    int lp = (wm * 4 + mb) * 16 + il;
    int ly = lp >> 6, lx = lp & 63;
    abase[mb] = (ly * 66 + lx) * 80 + kb * 16;
  }
  int boff[4];
#pragma unroll
  for (int nbi = 0; nbi < 4; ++nbi)
    boff[nbi] = ((wn * 4 + nbi) * 16 + il) * 64 + kb * 16;

  f32x4 acc[4][4];
#pragma unroll
  for (int mb = 0; mb < 4; ++mb)
#pragma unroll
    for (int nbi = 0; nbi < 4; ++nbi) {
      f32x4 z = {0.f, 0.f, 0.f, 0.f};
      acc[mb][nbi] = z;
    }

  const float* Fb = in + (size_t)b * CI * 4096;
  const char* WhB = (const char*)Wh;
  const char* WlB = (const char*)Wl;

  auto stageA2 = [&](int g) {
    const float* src = Fb + (size_t)g * 32 * 4096;
    for (int s = tid; s < ROWS * 66 * 8; s += 512) {
      int ciq = s & 7;
      int rest = s >> 3;
      int r = rest / 66, x = rest - r * 66;
      int row = y0 - 1 + r, col = x - 1;
      float a0 = 0.f, a1 = 0.f, a2 = 0.f, a3 = 0.f;
      if (row >= 0 && row < 64 && col >= 0 && col < 64) {
        const float* p = src + (size_t)(ciq * 4) * 4096 + row * 64 + col;
        a0 = p[0];
        a1 = p[4096];
        a2 = p[8192];
        a3 = p[12288];
      }
      u16 h0 = f2bf(a0), h1 = f2bf(a1), h2 = f2bf(a2), h3 = f2bf(a3);
      u16 l0 = f2bf(a0 - bf2f(h0)), l1 = f2bf(a1 - bf2f(h1));
      u16 l2 = f2bf(a2 - bf2f(h2)), l3 = f2bf(a3 - bf2f(h3));
      int off = (r * 66 + x) * 80 + ciq * 8;
      *(ushort4*)(lds_a + off) = make_ushort4(h0, h1, h2, h3);
      *(ushort4*)(lds_a + APL + off) = make_ushort4(l0, l1, l2, l3);
    }
  };

  for (int g = 0; g < NCHUNK; ++g) {
    __syncthreads();
    stageA2(g);
    __syncthreads();
#pragma unroll
    for (int tap = 0; tap < 9; ++tap) {
      const char* pb = WhB + (size_t)(g * 9 + tap) * (CO * 64);
      const char* pl = WlB + (size_t)(g * 9 + tap) * (CO * 64);
      bf16x8 bh[4], bl[4];
#pragma unroll
      for (int nbi = 0; nbi < 4; ++nbi) {
        bh[nbi] = *(const bf16x8*)(pb + boff[nbi]);
        bl[nbi] = *(const bf16x8*)(pl + boff[nbi]);
      }
      int ky = tap / 3, kx = tap - ky * 3;
      int toff = (ky * 66 + kx) * 80;
      bf16x8 avh[4], avl[4];
#pragma unroll
      for (int mb = 0; mb < 4; ++mb) {
        avh[mb] = *(const bf16x8*)(lds_a + abase[mb] + toff);
        avl[mb] = *(const bf16x8*)(lds_a + APL + abase[mb] + toff);
      }
#pragma unroll
      for (int mb = 0; mb < 4; ++mb)
#pragma unroll
        for (int nbi = 0; nbi < 4; ++nbi) {
          acc[mb][nbi] = __builtin_amdgcn_mfma_f32_16x16x32_bf16(
              avh[mb], bh[nbi], acc[mb][nbi], 0, 0, 0);
          acc[mb][nbi] = __builtin_amdgcn_mfma_f32_16x16x32_bf16(
              avh[mb], bl[nbi], acc[mb][nbi], 0, 0, 0);
          acc[mb][nbi] = __builtin_amdgcn_mfma_f32_16x16x32_bf16(
              avl[mb], bh[nbi], acc[mb][nbi], 0, 0, 0);
        }
    }
  }

  const int p0 = y0 * 64;
#pragma unroll
  for (int mb = 0; mb < 4; ++mb) {
    int pixb = p0 + (wm * 4 + mb) * 16 + kb * 4;
#pragma unroll
    for (int nbi = 0; nbi < 4; ++nbi) {
      int co = (wn * 4 + nbi) * 16 + il;
      float bv_ = bias[co];
      f32x4 a = acc[mb][nbi];
      float4 o = make_float4(fmaxf(a[0] + bv_, 0.f), fmaxf(a[1] + bv_, 0.f),
                             fmaxf(a[2] + bv_, 0.f), fmaxf(a[3] + bv_, 0.f));
      *(float4*)(out + (size_t)(b * CO + co) * 4096 + pixb) = o;
    }
  }
}

// ---------------------------------------------------------------- 1x1 fusion via MFMA bf16 hi/lo (exact)
__global__ __launch_bounds__(512) void fuse_mfma_k(const float* __restrict__ t3,
                                                   const u16* __restrict__ Wh,
                                                   const u16* __restrict__ Wl,
                                                   const float* __restrict__ bf,
                                                   float* __restrict__ a) {
  constexpr int APL = 128 * 80;
  __shared__ __align__(16) char lds_a[2 * APL];
  const int tid = threadIdx.x;
  const int b = blockIdx.y;
  const int p0 = blockIdx.x * 128;
  const int w = tid >> 6, l = tid & 63;
  const int wm = w >> 2, wn = w & 3;
  const int kb = l >> 4, il = l & 15;

  int abase[4];
#pragma unroll
  for (int mb = 0; mb < 4; ++mb)
    abase[mb] = ((wm * 4 + mb) * 16 + il) * 80 + kb * 16;
  int boff[4];
#pragma unroll
  for (int nbi = 0; nbi < 4; ++nbi)
    boff[nbi] = ((wn * 4 + nbi) * 16 + il) * 64 + kb * 16;

  f32x4 acc[4][4];
#pragma unroll
  for (int mb = 0; mb < 4; ++mb)
#pragma unroll
    for (int nbi = 0; nbi < 4; ++nbi) {
      f32x4 z = {0.f, 0.f, 0.f, 0.f};
      acc[mb][nbi] = z;
    }

  const char* WhB = (const char*)Wh;
  const char* WlB = (const char*)Wl;

  auto stageAB = [&](int c) {
    for (int s = tid; s < 128 * 8; s += 512) {
      int ciq = s & 7, px = s >> 3;
      int pg = p0 + px;
      u16 eh[4], el[4];
#pragma unroll
      for (int q = 0; q < 4; ++q) {
        int lc = c * 32 + ciq * 4 + q;
        float f = 0.f;
        if (lc < 4)
          f = t3[(size_t)b * 16384 + lc * 4096 + pg];
        else if (lc < 260)
          f = a[((size_t)b * 256 + (lc - 4)) * 4096 + pg];
        u16 h = f2bf(f);
        eh[q] = h;
        el[q] = f2bf(f - bf2f(h));
      }
      *(ushort4*)(lds_a + px * 80 + ciq * 8) = make_ushort4(eh[0], eh[1], eh[2], eh[3]);
      *(ushort4*)(lds_a + APL + px * 80 + ciq * 8) =
          make_ushort4(el[0], el[1], el[2], el[3]);
    }
  };

  for (int c = 0; c < 9; ++c) {
    __syncthreads();
    stageAB(c);
    __syncthreads();
    bf16x8 bh[4], bl[4];
#pragma unroll
    for (int nbi = 0; nbi < 4; ++nbi) {
      bh[nbi] = *(const bf16x8*)(WhB + (size_t)c * 16384 + boff[nbi]);
      bl[nbi] = *(const bf16x8*)(WlB + (size_t)c * 16384 + boff[nbi]);
    }
    bf16x8 avh[4], avl[4];
#pragma unroll
    for (int mb = 0; mb < 4; ++mb) {
      avh[mb] = *(const bf16x8*)(lds_a + abase[mb]);
      avl[mb] = *(const bf16x8*)(lds_a + APL + abase[mb]);
    }
#pragma unroll
    for (int mb = 0; mb < 4; ++mb)
#pragma unroll
      for (int nbi = 0; nbi < 4; ++nbi) {
        acc[mb][nbi] = __builtin_amdgcn_mfma_f32_16x16x32_bf16(
            avh[mb], bh[nbi], acc[mb][nbi], 0, 0, 0);
        acc[mb][nbi] = __builtin_amdgcn_mfma_f32_16x16x32_bf16(
            avh[mb], bl[nbi], acc[mb][nbi], 0, 0, 0);
        acc[mb][nbi] = __builtin_amdgcn_mfma_f32_16x16x32_bf16(
            avl[mb], bh[nbi], acc[mb][nbi], 0, 0, 0);
      }
  }

#pragma unroll
  for (int mb = 0; mb < 4; ++mb) {
    int pixb = p0 + (wm * 4 + mb) * 16 + kb * 4;
#pragma unroll
    for (int nbi = 0; nbi < 4; ++nbi) {
      int co = (wn * 4 + nbi) * 16 + il;
      float bv_ = bf[co];
      f32x4 v = acc[mb][nbi];
      float4 o = make_float4(v[0] + bv_, v[1] + bv_, v[2] + bv_, v[3] + bv_);
      *(float4*)(a + (size_t)(b * 256 + co) * 4096 + pixb) = o;
    }
  }
}

// ---------------------------------------------------------------- 9x9 s2 conv, MFMA fp16 2-pass, 16 waves
__global__ __launch_bounds__(1024) void conv9x9_mfma_k(const float* __restrict__ fused,
                                                       const u16* __restrict__ WTh,
                                                       const u16* __restrict__ WTl,
                                                       const float* __restrict__ bias,
                                                       float* __restrict__ praw) {
  constexpr int APLANE = 19 * 32 * 80;
  __shared__ __align__(16) char lds_a[2 * APLANE];
  const int tid = threadIdx.x;
  const int b = blockIdx.y, tile = blockIdx.x;
  const int p0 = tile * 128;
  const int oy0 = p0 / 28;
  const int w = tid >> 6, l = tid & 63;
  const int wm = w >> 3, wn = w & 7;
  const int kb = l >> 4, il = l & 15;

  int abase[4];
#pragma unroll
  for (int mb = 0; mb < 4; ++mb) {
    int p = p0 + (wm * 4 + mb) * 16 + il;
    int oy = p / 28, ox = p - oy * 28;
    abase[mb] = (2 * (oy - oy0)) * 2560 + ox * 80 + kb * 16;
  }
  int boff[2];
#pragma unroll
  for (int nbi = 0; nbi < 2; ++nbi)
    boff[nbi] = (wn * 32 + nbi * 16 + il) * 64 + kb * 16;

  f32x4 acc[4][2];
#pragma unroll
  for (int mb = 0; mb < 4; ++mb)
#pragma unroll
    for (int nbi = 0; nbi < 2; ++nbi) {
      f32x4 z = {0.f, 0.f, 0.f, 0.f};
      acc[mb][nbi] = z;
    }

  const float* Fb = fused + (size_t)b * 256 * 4096;
  const char* WhB = (const char*)WTh;
  const char* WlB = (const char*)WTl;

  auto stageA = [&](int g) {
    const float* src = Fb + (size_t)g * 32 * 4096;
    for (int s = tid; s < 19 * 63 * 8; s += 1024) {
      int ciq = s / 1197;
      int rem = s - ciq * 1197;
      int r = rem / 63, t63 = rem - r * 63;
      int x2 = (t63 < 32) ? 2 * t63 : 2 * (t63 - 32) + 1;
      int iy = 2 * oy0 + r;
      float a0 = 0.f, a1 = 0.f, a2 = 0.f, a3 = 0.f;
      if (iy < 64) {
        const float* pp0 = src + (size_t)(ciq * 4) * 4096 + iy * 64 + x2;
        a0 = pp0[0];
        a1 = pp0[4096];
        a2 = pp0[8192];
        a3 = pp0[12288];
      }
      u16 e0 = f2h(a0), e1 = f2h(a1), e2 = f2h(a2), e3 = f2h(a3);
      int off = (x2 & 1) * APLANE + (r * 32 + (x2 >> 1)) * 80 + ciq * 8;
      *(ushort4*)(lds_a + off) = make_ushort4(e0, e1, e2, e3);
    }
  };

  for (int g = 0; g < 8; ++g) {
    __syncthreads();
    stageA(g);
    __syncthreads();
#pragma unroll 3
    for (int t = 0; t < 81; ++t) {
      const char* pb = WhB + (size_t)(g * 81 + t) * 16384;
      const char* pl = WlB + (size_t)(g * 81 + t) * 16384;
      f16x8 bh[2], bl[2];
#pragma unroll
      for (int nbi = 0; nbi < 2; ++nbi) {
        bh[nbi] = *(const f16x8*)(pb + boff[nbi]);
        bl[nbi] = *(const f16x8*)(pl + boff[nbi]);
      }
      int ky = t / 9, kx = t - ky * 9;
      int toff = (kx & 1) * APLANE + ky * 2560 + (kx >> 1) * 80;
      f16x8 av[4];
#pragma unroll
      for (int mb = 0; mb < 4; ++mb)
        av[mb] = *(const f16x8*)(lds_a + abase[mb] + toff);
#pragma unroll
      for (int mb = 0; mb < 4; ++mb)
#pragma unroll
        for (int nbi = 0; nbi < 2; ++nbi) {
          acc[mb][nbi] = __builtin_amdgcn_mfma_f32_16x16x32_f16(
              av[mb], bh[nbi], acc[mb][nbi], 0, 0, 0);
          acc[mb][nbi] = __builtin_amdgcn_mfma_f32_16x16x32_f16(
              av[mb], bl[nbi], acc[mb][nbi], 0, 0, 0);
        }
    }
  }

#pragma unroll
  for (int mb = 0; mb < 4; ++mb) {
    int pixb = p0 + (wm * 4 + mb) * 16 + kb * 4;
    if (pixb < 784) {
#pragma unroll
      for (int nbi = 0; nbi < 2; ++nbi) {
        int co = wn * 32 + nbi * 16 + il;
        float bv_ = bias[co];
        f32x4 v = acc[mb][nbi];
        float4 o = make_float4(v[0] + bv_, v[1] + bv_, v[2] + bv_, v[3] + bv_);
        *(float4*)(praw + (size_t)(b * 256 + co) * 784 + pixb) = o;
      }
    }
  }
}

// ---------------------------------------------------------------- fused squash + u_hat (fp32 out)
__global__ __launch_bounds__(256) void squash_uhat_k(const float* __restrict__ praw,
                                                     const float* __restrict__ w_r,
                                                     float* __restrict__ u_hat) {
  int i = blockIdx.x * 256 + threadIdx.x;  // 25088
  int b = blockIdx.y;
  int prim = i / 784, pix = i - prim * 784;
  const float* pp = praw + ((size_t)b * 256 + prim * 8) * 784 + pix;
  float xv[8];
  float sn = 0.f;
#pragma unroll
  for (int d = 0; d < 8; ++d) {
    xv[d] = pp[(size_t)d * 784];
    sn += xv[d] * xv[d];
  }
  float scale = sn / ((1.f + sn) * sqrtf(sn + 1e-8f));
  float4 ua = make_float4(xv[0] * scale, xv[1] * scale, xv[2] * scale, xv[3] * scale);
  float4 ub = make_float4(xv[4] * scale, xv[5] * scale, xv[6] * scale, xv[7] * scale);

  const float4* wr = (const float4*)(w_r + (size_t)i * 256);
  float res[32];
#pragma unroll
  for (int od = 0; od < 32; ++od) {
    float4 wa = wr[od * 2], wb = wr[od * 2 + 1];
    res[od] = wa.x * ua.x + wa.y * ua.y + wa.z * ua.z + wa.w * ua.w +
              wb.x * ub.x + wb.y * ub.y + wb.z * ub.z + wb.w * ub.w;
  }
  float4* dst = (float4*)(u_hat + ((size_t)b * 25088 + i) * 32);
#pragma unroll
  for (int q = 0; q < 8; ++q)
    dst[q] = make_float4(res[4 * q], res[4 * q + 1], res[4 * q + 2], res[4 * q + 3]);
}

// ---------------------------------------------------------------- routing iter0: s_j partials (c = 0.5)
__global__ __launch_bounds__(256) void route_sj_k(const float* __restrict__ u_hat,
                                                  float* __restrict__ sj_part) {
  int b = blockIdx.x;
  int seg = blockIdx.y;
  int t = threadIdx.x;
  float acc[32];
#pragma unroll
  for (int j = 0; j < 32; ++j) acc[j] = 0.f;
  int i0 = seg * 3136;
  for (int i = i0 + t; i < i0 + 3136; i += 256) {
    const float4* uh = (const float4*)(u_hat + ((size_t)b * 25088 + i) * 32);
#pragma unroll
    for (int q = 0; q < 4; ++q) {
      float4 va = uh[q];
      acc[4 * q + 0] += 0.5f * va.x;
      acc[4 * q + 1] += 0.5f * va.y;
      acc[4 * q + 2] += 0.5f * va.z;
      acc[4 * q + 3] += 0.5f * va.w;
      float4 vb = uh[4 + q];
      acc[16 + 4 * q + 0] += 0.5f * vb.x;
      acc[16 + 4 * q + 1] += 0.5f * vb.y;
      acc[16 + 4 * q + 2] += 0.5f * vb.z;
      acc[16 + 4 * q + 3] += 0.5f * vb.w;
    }
  }
#pragma unroll
  for (int j = 0; j < 32; ++j) {
    acc[j] += __shfl_down(acc[j], 32);
    acc[j] += __shfl_down(acc[j], 16);
    acc[j] += __shfl_down(acc[j], 8);
    acc[j] += __shfl_down(acc[j], 4);
    acc[j] += __shfl_down(acc[j], 2);
    acc[j] += __shfl_down(acc[j], 1);
  }
  __shared__ float red[4][32];
  int wave = t >> 6, lane = t & 63;
  if (lane == 0) {
#pragma unroll
    for (int j = 0; j < 32; ++j) red[wave][j] = acc[j];
  }
  __syncthreads();
  if (t < 32) {
    float s = red[0][t] + red[1][t] + red[2][t] + red[3][t];
    sj_part[((size_t)b * 8 + seg) * 32 + t] = s;
  }
}

// ---------------------------------------------------------------- routing fused v+upd+sj (iters 1,2)
__global__ __launch_bounds__(256) void route_fsj_k(const float* __restrict__ u_hat,
                                                   const float* __restrict__ sjp_in,
                                                   float* __restrict__ b_ij,
                                                   float* __restrict__ sjp_out, int first) {
  int b = blockIdx.x;
  int seg = blockIdx.y;
  int t = threadIdx.x;
  __shared__ float vsh[32];
  if (t < 32) {
    float s = 0.f;
#pragma unroll
    for (int sg = 0; sg < 8; ++sg) s += sjp_in[((size_t)b * 8 + sg) * 32 + t];
    float sn = s * s;
    vsh[t] = sn * s / ((1.f + sn) * sqrtf(sn + 1e-8f));
  }
  __syncthreads();
  float vp[32];
#pragma unroll
  for (int j = 0; j < 32; ++j) vp[j] = vsh[j];

  float acc[32];
#pragma unroll
  for (int j = 0; j < 32; ++j) acc[j] = 0.f;
  int i0 = seg * 3136;
  for (int i = i0 + t; i < i0 + 3136; i += 256) {
    const float4* uhp = (const float4*)(u_hat + ((size_t)b * 25088 + i) * 32);
    float4 uh[8];
#pragma unroll
    for (int q = 0; q < 8; ++q) uh[q] = uhp[q];
    float e0 = 0.f, e1 = 0.f;
#pragma unroll
    for (int q = 0; q < 4; ++q) {
      e0 += uh[q].x * vp[4 * q] + uh[q].y * vp[4 * q + 1] + uh[q].z * vp[4 * q + 2] +
            uh[q].w * vp[4 * q + 3];
      e1 += uh[4 + q].x * vp[16 + 4 * q] + uh[4 + q].y * vp[16 + 4 * q + 1] +
            uh[4 + q].z * vp[16 + 4 * q + 2] + uh[4 + q].w * vp[16 + 4 * q + 3];
    }
    size_t o = ((size_t)b * 25088 + i) * 2;
    float b0, b1;
    if (first) {
      b0 = e0;
      b1 = e1;
      b_ij[o + 0] = e0;
      b_ij[o + 1] = e1;
    } else {
      b0 = b_ij[o + 0] + e0;
      b1 = b_ij[o + 1] + e1;
    }
    float m = fmaxf(b0, b1);
    float x0 = expf(b0 - m), x1 = expf(b1 - m);
    float inv = 1.f / (x0 + x1);
    float c0 = x0 * inv, c1 = x1 * inv;
#pragma unroll
    for (int q = 0; q < 4; ++q) {
      acc[4 * q + 0] += c0 * uh[q].x;
      acc[4 * q + 1] += c0 * uh[q].y;
      acc[4 * q + 2] += c0 * uh[q].z;
      acc[4 * q + 3] += c0 * uh[q].w;
      acc[16 + 4 * q + 0] += c1 * uh[4 + q].x;
      acc[16 + 4 * q + 1] += c1 * uh[4 + q].y;
      acc[16 + 4 * q + 2] += c1 * uh[4 + q].z;
      acc[16 + 4 * q + 3] += c1 * uh[4 + q].w;
    }
  }
#pragma unroll
  for (int j = 0; j < 32; ++j) {
    acc[j] += __shfl_down(acc[j], 32);
    acc[j] += __shfl_down(acc[j], 16);
    acc[j] += __shfl_down(acc[j], 8);
    acc[j] += __shfl_down(acc[j], 4);
    acc[j] += __shfl_down(acc[j], 2);
    acc[j] += __shfl_down(acc[j], 1);
  }
  __shared__ float red[4][32];
  int wave = t >> 6, lane = t & 63;
  if (lane == 0) {
#pragma unroll
    for (int j = 0; j < 32; ++j) red[wave][j] = acc[j];
  }
  __syncthreads();
  if (t < 32) {
    float s = red[0][t] + red[1][t] + red[2][t] + red[3][t];
    sjp_out[((size_t)b * 8 + seg) * 32 + t] = s;
  }
}

// ---------------------------------------------------------------- routing: finalize v -> out
__global__ __launch_bounds__(256) void route_fin_k(const float* __restrict__ sj_part,
                                                   float* __restrict__ v,
                                                   float* __restrict__ out, int final_it) {
  int idx = blockIdx.x * 256 + threadIdx.x;
  if (idx >= BSZ * 32) return;
  int b = idx >> 5, j = idx & 31;
  float s = 0.f;
#pragma unroll
  for (int seg = 0; seg < 8; ++seg) s += sj_part[((size_t)b * 8 + seg) * 32 + j];
  float sn = s * s;
  float vv = sn * s / ((1.f + sn) * sqrtf(sn + 1e-8f));
  v[idx] = vv;
  if (final_it) out[idx] = fabsf(vv);
}

// ================================================================ launch
extern "C" void kernel_launch(void* const* d_in, const int* in_sizes, int n_in,
                              void* d_out, int out_size, void* d_ws, size_t ws_size,
                              hipStream_t stream) {
  (void)in_sizes; (void)n_in; (void)out_size;
  const float* x    = (const float*)d_in[0];
  const float* w_t1 = (const float*)d_in[1];
  const float* b_t1 = (const float*)d_in[2];
  const float* w_t2 = (const float*)d_in[3];
  const float* b_t2 = (const float*)d_in[4];
  const float* w_t3 = (const float*)d_in[5];
  const float* b_t3 = (const float*)d_in[6];
  const float* w_s1 = (const float*)d_in[7];
  const float* b_s1 = (const float*)d_in[8];
  const float* w_s2 = (const float*)d_in[9];
  const float* b_s2 = (const float*)d_in[10];
  const float* w_s3 = (const float*)d_in[11];
  const float* b_s3 = (const float*)d_in[12];
  const float* w_f  = (const float*)d_in[13];
  const float* b_f  = (const float*)d_in[14];
  const float* w_p  = (const float*)d_in[15];
  const float* b_p  = (const float*)d_in[16];
  const float* w_r  = (const float*)d_in[17];
  float* out = (float*)d_out;

  char* ws = (char*)d_ws;
  if (ws_size < 238854144ull) return;
  // region 0: fused (fp32) -> uhat (fp32, 102.8MB)
  float* fused = (float*)(ws + 0);
  float* uhat  = (float*)(ws + 0);
  // region 1 (134,217,728): s2q -> praw / b_ij
  float* s2q   = (float*)(ws + 134217728);
  float* praw  = (float*)(ws + 134217728);
  float* b_ij  = (float*)(ws + 185597952);
  // region 2 (201,326,592): s1 -> t1/t2/t3/wTh/wTl
  float* s1    = (float*)(ws + 201326592);
  float* t1    = (float*)(ws + 201326592);
  float* t2    = (float*)(ws + 201850880);
  float* t3    = (float*)(ws + 202899456);
  u16*   wTh   = (u16*)  (ws + 204996608);
  u16*   wTl   = (u16*)  (ws + 215613440);
  // tail (234,881,024): persistent small tables
  u16*   w3a_h = (u16*)  (ws + 234881024);
  u16*   w3a_l = (u16*)  (ws + 235028480);
  u16*   w3b_h = (u16*)  (ws + 235175936);
  u16*   w3b_l = (u16*)  (ws + 235765760);
  u16*   wf1_h = (u16*)  (ws + 236355584);
  u16*   wf1_l = (u16*)  (ws + 236503040);
  float* sjpA  = (float*)(ws + 236650496);
  float* sjpB  = (float*)(ws + 236683264);
  float* vbuf  = (float*)(ws + 236716032);

  // small weight tables (tail region -- never clobbered)
  transpose_w3_k<128, 2><<<18, 256, 0, stream>>>(w_s2, w3a_h, w3a_l);
  transpose_w3_k<256, 4><<<36, 256, 0, stream>>>(w_s3, w3b_h, w3b_l);
  transpose_wf1_k<<<9, 256, 0, stream>>>(w_f, wf1_h, wf1_l);

  // spectral: s1 scalar conv, then s2 MFMA conv (consumes s1)
  conv3x3_relu_k<1, 1><<<dim3(16, 4, BSZ), 256, 0, stream>>>(x, w_s1, b_s1, s1, 64);
  conv3x3_mfma_k<4, 2, 2, 128><<<dim3(16, BSZ), 512, 0, stream>>>(s1, w3a_h, w3a_l, b_s2, s2q);

  // s1 now dead: temporal branch (3 kernels, full grid) + 9x9 weight tables
  conv1d_relu_k<<<512, 256, 0, stream>>>(x, w_t1, b_t1, t1, 64, 64);
  conv1d_relu_k<<<1024, 256, 0, stream>>>(t1, w_t2, b_t2, t2, 64, 128);
  conv1d_relu_k<<<2048, 256, 0, stream>>>(t2, w_t3, b_t3, t3, 128, 256);
  transpose_wp_k<<<648, 256, 0, stream>>>(w_p, wTh, wTl);

  // s3 MFMA conv -> fused
  conv3x3_mfma_k<2, 4, 4, 256><<<dim3(32, BSZ), 512, 0, stream>>>(s2q, w3b_h, w3b_l, b_s3, fused);

  // fusion via MFMA, in-place on fused (exact bf16 hi/lo)
  fuse_mfma_k<<<dim3(32, BSZ), 512, 0, stream>>>(t3, wf1_h, wf1_l, b_f, fused);

  // primary capsules via MFMA fp16 2-pass, 16 waves (praw over dead s2q)
  conv9x9_mfma_k<<<dim3(7, BSZ), 1024, 0, stream>>>(fused, wTh, wTl, b_p, praw);

  // fused squash + u_hat (fp32; overwrites fused region)
  squash_uhat_k<<<dim3(98, BSZ), 256, 0, stream>>>(praw, w_r, uhat);

  // dynamic routing, 3 iterations (v computed inline in fsj; sjp ping-pong)
  route_sj_k<<<dim3(BSZ, 8), 256, 0, stream>>>(uhat, sjpA);
  route_fsj_k<<<dim3(BSZ, 8), 256, 0, stream>>>(uhat, sjpA, b_ij, sjpB, 1);
  route_fsj_k<<<dim3(BSZ, 8), 256, 0, stream>>>(uhat, sjpB, b_ij, sjpA, 0);
  route_fin_k<<<4, 256, 0, stream>>>(sjpA, vbuf, out, 1);
}